// Round 9
// baseline (6984.801 us; speedup 1.0000x reference)
//
#include <hip/hip_runtime.h>
#include <hip/hip_bf16.h>

#define B_ 256
#define S_ 512
#define H_ 1024
#define C_ 10

typedef unsigned long long u64;
typedef __attribute__((ext_vector_type(8))) short s8v;      // 8 bf16 (4 VGPRs) - MFMA A/B frag
typedef __attribute__((ext_vector_type(4))) float f4v;      // MFMA C/D frag

// ---------------- workspace layout (bytes) ----------------
// [0, 1024)        : flags[4 groups][4 slices][16 u32] — one 64 B line per (group, k-slice);
//                    block (m,n) stores slot (n&15) of line (m,n>>4). 16 writers/line.
// [32768, +512K)   : xT  (S x B fp32)
// [+512K, +512K)   : h0  (B x H bf16), zeroed per launch
// [+512K, +512K)   : h1
// [+512K, +8M)     : Wp  (packed bf16 weights, fragment-linear, MFMA A operand)
#define HDR_ 32768

__global__ void prep_w(const float* __restrict__ wg, const float* __restrict__ wi,
                       const float* __restrict__ wf, const float* __restrict__ wo,
                       __hip_bfloat16* __restrict__ Wp) {
    int idx = blockIdx.x * 256 + threadIdx.x;        // 524288 groups of 8
    int g   = idx >> 17;
    int rem = idx & 131071;
    int o   = rem >> 7;                              // out col 0..1023
    int kg  = rem & 127;                             // k0 = kg*8
    const float* src = (g == 0 ? wg : g == 1 ? wi : g == 2 ? wf : wo) + o * H_ + kg * 8;
    int kc   = kg >> 2;
    int quad = kg & 3;
    int lane = quad * 16 + (o & 15);
    int ot   = o >> 4;
    int blk  = (g * 64 + ot) * 32 + kc;
    __hip_bfloat16* dst = Wp + blk * 512 + lane * 8;
#pragma unroll
    for (int j = 0; j < 8; ++j) dst[j] = __float2bfloat16(src[j]);
}

__global__ void prep_x(const float* __restrict__ x, float* __restrict__ xT) {
    int i = blockIdx.x * 256 + threadIdx.x;          // 131072
    int t = i >> 8, b = i & 255;
    xT[i] = x[b * S_ + t];
}

__device__ __forceinline__ float sigmoid_f(float x) { return 1.0f / (1.0f + __expf(-x)); }
__device__ __forceinline__ float tanh_f(float x)    { return 2.0f / (1.0f + __expf(-2.0f * x)) - 1.0f; }

__device__ __forceinline__ float bf2f(unsigned short u) {
    union { unsigned i; float f; } x; x.i = ((unsigned)u) << 16; return x.f;
}
__device__ __forceinline__ unsigned short f2bf(float f) {
    union { __hip_bfloat16 h; unsigned short s; } x; x.h = __float2bfloat16(f); return x.s;
}

__device__ __forceinline__ void waitcnt_vm0() { asm volatile("s_waitcnt vmcnt(0)" ::: "memory"); }

__global__ __launch_bounds__(256, 1) void lstm_main(
    const float* __restrict__ xT,
    const float* __restrict__ wgx, const float* __restrict__ wix,
    const float* __restrict__ wfx, const float* __restrict__ wox,
    const float* __restrict__ bg,  const float* __restrict__ bi,
    const float* __restrict__ bf,  const float* __restrict__ bo,
    const __hip_bfloat16* __restrict__ Wp,
    __hip_bfloat16* __restrict__ h0, __hip_bfloat16* __restrict__ h1,
    const float* __restrict__ wph, const float* __restrict__ bp,
    float* __restrict__ out,
    unsigned* __restrict__ flags)
{
    // split-K partial exchange: [src_wave][gate][rowtile][lane] = 64 KB
    __shared__ f4v part[4][4][4][64];

    const int tid  = threadIdx.x;
    const int wgid = blockIdx.x;         // 256 blocks x 256 threads
    // XCD-affinity remap: group m lives on XCDs {2m, 2m+1} under round-robin dispatch
    const int m    = (wgid & 7) >> 1;                 // batch group 0..3 (64 rows)
    const int n    = ((wgid >> 3) << 1) | (wgid & 1); // out-tile 0..63 (16 cols/gate)
    const int w    = tid >> 6;           // wave 0..3: k-slice owner AND row-subtile owner
    const int l    = tid & 63;
    const int quad = l >> 4;
    const int l16  = l & 15;
    const int b    = m * 64 + w * 16 + l16;  // this lane's batch row for epilogue/store
    const int out0 = n * 16 + quad * 4;      // first of this lane's 4 hidden cols (D rows)

    // ---- W resident in REGISTERS: 4 gates x 8 kc (k-slice [256w,256w+256)) = 128 VGPRs
    s8v Wreg[32];
    {
        const s8v* Wv = (const s8v*)Wp;
#pragma unroll
        for (int g = 0; g < 4; ++g)
#pragma unroll
            for (int j = 0; j < 8; ++j)
                Wreg[g * 8 + j] = Wv[((size_t)((g * 64 + n) * 32 + (8 * w + j))) * 64 + l];
    }

    // per-lane gate params for the 4 consecutive hidden cols
    float wxg[4], wxi[4], wxf[4], wxo[4], bbg[4], bbi[4], bbf[4], bbo[4];
    *(float4*)wxg = *(const float4*)(wgx + out0);
    *(float4*)wxi = *(const float4*)(wix + out0);
    *(float4*)wxf = *(const float4*)(wfx + out0);
    *(float4*)wxo = *(const float4*)(wox + out0);
    *(float4*)bbg = *(const float4*)(bg + out0);
    *(float4*)bbi = *(const float4*)(bi + out0);
    *(float4*)bbf = *(const float4*)(bf + out0);
    *(float4*)bbo = *(const float4*)(bo + out0);

    float cs[4] = {0.f, 0.f, 0.f, 0.f};     // persistent cell state (rowtile w, cols out0..+3)

    // flag lines: wave w polls line (m,slice=w); block stores slot (n&15) of line (m,n>>4)
    const unsigned* myline = flags + (m * 4 + w) * 16;
    unsigned*       myflag = flags + (m * 4 + (n >> 4)) * 16 + (n & 15);

    __syncthreads();

    for (int t = 0; t < S_; ++t) {
        const __hip_bfloat16* hin  = (t & 1) ? h1 : h0;
        __hip_bfloat16*       hout = (t & 1) ? h0 : h1;

        float xa = xT[t * B_ + b];           // independent of h

        // wait for k-slice w of h(t): one 64 B line, 4 B/lane + ballot
        for (;;) {
            unsigned v = __hip_atomic_load(myline + (l & 15), __ATOMIC_RELAXED, __HIP_MEMORY_SCOPE_AGENT);
            if (__ballot(v < (unsigned)t) == 0ull) break;
            __builtin_amdgcn_s_sleep(2);
        }

        // load h fragments: rowtile rt (rows 16rt..16rt+16 of group), kc in slice w
        // lane: h[m*64 + 16rt + l16][(8w+j)*32 + quad*8 .. +8]
        // row stride = 1024 bf16 = 2048 B = 256 u64  (r8 bug: was 128)
        u64 hq[64];
#pragma unroll
        for (int rt = 0; rt < 4; ++rt) {
            const u64* hb = (const u64*)hin + (size_t)(m * 64 + 16 * rt + l16) * 256 + (8 * w) * 8 + quad * 2;
#pragma unroll
            for (int j = 0; j < 8; ++j) {
                hq[(rt * 8 + j) * 2]     = __hip_atomic_load(hb + j * 8,     __ATOMIC_RELAXED, __HIP_MEMORY_SCOPE_AGENT);
                hq[(rt * 8 + j) * 2 + 1] = __hip_atomic_load(hb + j * 8 + 1, __ATOMIC_RELAXED, __HIP_MEMORY_SCOPE_AGENT);
            }
        }

        // partial GEMM over this wave's K-slice: A = register W, B = h frags
        f4v acc[16];
#pragma unroll
        for (int i = 0; i < 16; ++i) acc[i] = (f4v){0.f, 0.f, 0.f, 0.f};
#pragma unroll
        for (int rt = 0; rt < 4; ++rt) {
#pragma unroll
            for (int j = 0; j < 8; ++j) {
                union { u64 q[2]; s8v v; } hf_;
                hf_.q[0] = hq[(rt * 8 + j) * 2]; hf_.q[1] = hq[(rt * 8 + j) * 2 + 1];
                s8v hv = hf_.v;
#pragma unroll
                for (int g = 0; g < 4; ++g)
                    acc[g * 4 + rt] = __builtin_amdgcn_mfma_f32_16x16x32_bf16(Wreg[g * 8 + j], hv, acc[g * 4 + rt], 0, 0, 0);
            }
        }

        // exchange partials: write rowtiles != w, keep own
#pragma unroll
        for (int g = 0; g < 4; ++g)
#pragma unroll
            for (int rt = 0; rt < 4; ++rt)
                if (rt != w) part[w][g][rt][l] = acc[g * 4 + rt];
        __syncthreads();                     // SYNC A: partials visible

        f4v fin[4];
#pragma unroll
        for (int g = 0; g < 4; ++g) {
            fin[g] = acc[g * 4 + w];
#pragma unroll
            for (int sw = 0; sw < 4; ++sw)
                if (sw != w) fin[g] += part[sw][g][w][l];
        }

        // epilogue: D row (quad*4+r) = hidden col out0+r, D col (l16) = batch b
        unsigned short hs[4];
#pragma unroll
        for (int r = 0; r < 4; ++r) {
            float pg = fin[0][r] + xa * wxg[r] + bbg[r];
            float pi = fin[1][r] + xa * wxi[r] + bbi[r];
            float pf = fin[2][r] + xa * wxf[r] + bbf[r];
            float po = fin[3][r] + xa * wxo[r] + bbo[r];
            float gv = tanh_f(pg);
            float iv = sigmoid_f(pi);
            float fv = sigmoid_f(pf);
            float ov = sigmoid_f(po);
            float cn = gv * iv + cs[r] * fv;
            cs[r] = cn;
            hs[r] = f2bf(tanh_f(cn) * ov);
        }
        union { unsigned short s[4]; u64 q; } hp_;
        hp_.s[0] = hs[0]; hp_.s[1] = hs[1]; hp_.s[2] = hs[2]; hp_.s[3] = hs[3];
        __hip_atomic_store((u64*)(hout + b * H_ + out0), hp_.q,
                           __ATOMIC_RELAXED, __HIP_MEMORY_SCOPE_AGENT);
        waitcnt_vm0();                       // h store ack'ed at LLC
        __syncthreads();                     // SYNC B: all waves stored; part[] reusable
        if (tid == 0)
            __hip_atomic_store(myflag, (unsigned)(t + 1), __ATOMIC_RELAXED, __HIP_MEMORY_SCOPE_AGENT);
    }

    // wait for ALL of final h (4 lines x 16 flags, one per lane)
    for (;;) {
        unsigned v = __hip_atomic_load(flags + (m * 4 + (l >> 4)) * 16 + (l & 15),
                                       __ATOMIC_RELAXED, __HIP_MEMORY_SCOPE_AGENT);
        if (__ballot(v < (unsigned)S_) == 0ull) break;
        __builtin_amdgcn_s_sleep(2);
    }

    // projection restricted to own group's rows: out[row][cc], rows [64m, 64m+64)
    const __hip_bfloat16* hf = h0;           // t=511 (odd) wrote h0
    int wig = n * 4 + w;                     // wave index in group, 0..255
    for (int p = wig; p < 64 * C_; p += 256) {
        int row = m * 64 + p / C_;
        int cc  = p % C_;
        const u64* hr = (const u64*)(hf + row * H_);
        const float* wr = wph + cc * H_;
        float acc2 = 0.f;
#pragma unroll
        for (int j = 0; j < 4; ++j) {
            int k = j * 256 + l * 4;
            u64 hv4 = __hip_atomic_load(hr + (k >> 2), __ATOMIC_RELAXED, __HIP_MEMORY_SCOPE_AGENT);
            union { u64 q; unsigned short s[4]; } u_; u_.q = hv4;
            float4 wv = *(const float4*)(wr + k);
            acc2 += bf2f(u_.s[0]) * wv.x + bf2f(u_.s[1]) * wv.y
                  + bf2f(u_.s[2]) * wv.z + bf2f(u_.s[3]) * wv.w;
        }
#pragma unroll
        for (int off = 32; off > 0; off >>= 1) acc2 += __shfl_down(acc2, off, 64);
        if (l == 0) out[row * C_ + cc] = acc2 + bp[cc];
    }
}

extern "C" void kernel_launch(void* const* d_in, const int* in_sizes, int n_in,
                              void* d_out, int out_size, void* d_ws, size_t ws_size,
                              hipStream_t stream) {
    const float* xx  = (const float*)d_in[0];
    const float* wgx = (const float*)d_in[1];
    const float* wix = (const float*)d_in[2];
    const float* wfx = (const float*)d_in[3];
    const float* wox = (const float*)d_in[4];
    const float* wgh = (const float*)d_in[5];
    const float* wih = (const float*)d_in[6];
    const float* wfh = (const float*)d_in[7];
    const float* woh = (const float*)d_in[8];
    const float* wph = (const float*)d_in[9];
    const float* bg  = (const float*)d_in[10];
    const float* bi  = (const float*)d_in[11];
    const float* bf  = (const float*)d_in[12];
    const float* bo  = (const float*)d_in[13];
    const float* bp  = (const float*)d_in[14];
    float* out = (float*)d_out;

    char* ws = (char*)d_ws;
    unsigned*       flags = (unsigned*)ws;                  // 1 KB used
    float*          xT = (float*)(ws + HDR_);
    __hip_bfloat16* h0 = (__hip_bfloat16*)(ws + HDR_ + 524288);
    __hip_bfloat16* h1 = (__hip_bfloat16*)(ws + HDR_ + 2 * 524288);
    __hip_bfloat16* Wp = (__hip_bfloat16*)(ws + HDR_ + 3 * 524288);

    hipMemsetAsync(ws, 0, HDR_, stream);                  // flags = 0
    hipMemsetAsync(h0, 0, 524288, stream);                // h_0 = 0
    prep_x<<<512, 256, 0, stream>>>(xx, xT);
    prep_w<<<2048, 256, 0, stream>>>(wgh, wih, wfh, woh, Wp);
    lstm_main<<<256, 256, 0, stream>>>(xT, wgx, wix, wfx, wox, bg, bi, bf, bo,
                                       Wp, h0, h1, wph, bp, out, flags);
}